// Round 7
// baseline (600.352 us; speedup 1.0000x reference)
//
#include <hip/hip_runtime.h>

// ---------------------------------------------------------------- types
typedef __bf16  bf16x8 __attribute__((ext_vector_type(8)));
typedef float   f32x4  __attribute__((ext_vector_type(4)));

typedef const __attribute__((address_space(1))) void* gas_p;
typedef __attribute__((address_space(3))) void*       las_p;

__device__ __forceinline__ void glds16(const void* g, void* l) {
  // global -> LDS direct, 16B per lane; LDS dst is wave-uniform base + lane*16
  __builtin_amdgcn_global_load_lds((gas_p)g, (las_p)l, 16, 0, 0);
}

__device__ __forceinline__ ushort f2bf(float f) {  // RNE float->bf16
  unsigned u = __float_as_uint(f);
  u += 0x7fffu + ((u >> 16) & 1u);
  return (ushort)(u >> 16);
}

__device__ __forceinline__ void barx() {  // raw barrier w/ compiler memory fences
  asm volatile("" ::: "memory");
  __builtin_amdgcn_s_barrier();
  asm volatile("" ::: "memory");
}
#define WAITVM(N) asm volatile("s_waitcnt vmcnt(" #N ")" ::: "memory")

// ---------------------------------------------------------------- weight cast + transpose  w[K][N] f32 -> wT[N][K] bf16
__global__ __launch_bounds__(256) void castT_k(const float* __restrict__ w,
                                               ushort* __restrict__ wT,
                                               const int Kd, const int Nd) {
  __shared__ float t[32][33];
  const int nb = blockIdx.x * 32, kb = blockIdx.y * 32;
  const int tx = threadIdx.x & 31, ty = threadIdx.x >> 5;  // 32 x 8
#pragma unroll
  for (int r = 0; r < 32; r += 8)
    t[ty + r][tx] = w[(size_t)(kb + ty + r) * Nd + nb + tx];
  __syncthreads();
#pragma unroll
  for (int r = 0; r < 32; r += 8)
    wT[(size_t)(nb + ty + r) * Kd + kb + tx] = f2bf(t[tx][ty + r]);
}

// ---------------------------------------------------------------- LayerNorm (d=1024), fp32 in -> bf16 out
__global__ __launch_bounds__(256) void ln_k(const float* __restrict__ x,
                                            const float* __restrict__ gam,
                                            const float* __restrict__ bet,
                                            ushort* __restrict__ out) {
  const int row = blockIdx.x, tid = threadIdx.x;
  const float4 v = ((const float4*)(x + (size_t)row * 1024))[tid];
  float s  = v.x + v.y + v.z + v.w;
  float sq = v.x * v.x + v.y * v.y + v.z * v.z + v.w * v.w;
#pragma unroll
  for (int o = 32; o > 0; o >>= 1) { s += __shfl_xor(s, o); sq += __shfl_xor(sq, o); }
  __shared__ float red[8];
  const int wid = tid >> 6, lane = tid & 63;
  if (lane == 0) { red[wid] = s; red[4 + wid] = sq; }
  __syncthreads();
  s  = red[0] + red[1] + red[2] + red[3];
  sq = red[4] + red[5] + red[6] + red[7];
  const float mu   = s * (1.0f / 1024.0f);
  const float var  = sq * (1.0f / 1024.0f) - mu * mu;
  const float rstd = rsqrtf(var + 1e-5f);
  const float4 gv = ((const float4*)gam)[tid];
  const float4 bv = ((const float4*)bet)[tid];
  ushort4 o4;
  o4.x = f2bf((v.x - mu) * rstd * gv.x + bv.x);
  o4.y = f2bf((v.y - mu) * rstd * gv.y + bv.y);
  o4.z = f2bf((v.z - mu) * rstd * gv.z + bv.z);
  o4.w = f2bf((v.w - mu) * rstd * gv.w + bv.w);
  ((ushort4*)(out + (size_t)row * 1024))[tid] = o4;
}

// ---------------------------------------------------------------- V [B,H,T,64] -> Vt [B,H,64,T]  (bf16)
__global__ __launch_bounds__(256) void vtrans_k(const ushort* __restrict__ Vn,
                                                ushort* __restrict__ Vt) {
  const int bh = blockIdx.y, i0 = blockIdx.x * 64, tid = threadIdx.x;
  __shared__ ushort t[64][65];
  const ushort* src = Vn + (size_t)bh * (2048 * 64);
#pragma unroll
  for (int kk = 0; kk < 16; ++kk) {
    const int e = tid + kk * 256, r = e >> 6, c = e & 63;
    t[r][c] = src[(size_t)(i0 + r) * 64 + c];
  }
  __syncthreads();
  ushort* dst = Vt + (size_t)bh * (64 * 2048);
#pragma unroll
  for (int kk = 0; kk < 16; ++kk) {
    const int e = tid + kk * 256, r = e >> 6, c = e & 63;  // r = dh, c = i
    dst[(size_t)r * 2048 + i0 + c] = t[c][r];
  }
}

// ---------------------------------------------------------------- GEMM v2: 256-wide N tile, BK=64, 8 waves, 4-phase
// A[M][K] bf16 x Bt[N][K] bf16. BM = 32*MF (256 for MF=8, 128 for MF=4).
// Per-wave output: (MF*16) x 64 = MF x 4 frags of 16x16. LDS double-buffered,
// split by K-halves (32 cols each); counted vmcnt placed BEFORE closing barriers
// (wait-then-barrier publishes other waves' glds). XOR swizzle col^=((row>>1)&3)<<4
// applied on write (pre-swizzled global src) and read -> 2-way conflicts (free).
// Phases per K-tile: P0{rd A kk0 + B n01 kk0; stage A.k0'; MFMA 16} P1{rd B n23;
// stage B.k0'; MFMA 16; vmcnt} P2/P3 same for kk1.
template <int MF, int EPI>
__global__ __launch_bounds__(512, 2) void gemm2_k(
    const ushort* __restrict__ A, const ushort* __restrict__ Bt,
    const int M, const int N, const int K,
    const float* __restrict__ bias,
    const float* __restrict__ resid,
    float* __restrict__ outf,
    ushort* __restrict__ outb,
    ushort* __restrict__ qo, ushort* __restrict__ ko, ushort* __restrict__ vo) {
  constexpr int BM = MF * 32;
  constexpr int GA = MF / 4;           // glds calls per A k-half (2 or 1)
  extern __shared__ ushort lds_u[];
  ushort* aL = lds_u;                  // [2 buf][2 kh][BM][32]
  ushort* bL = lds_u + 4 * BM * 32;    // [2 buf][2 kh][256][32]

  const int tid = threadIdx.x, wid = tid >> 6, lane = tid & 63;
  const int l15 = lane & 15, g = lane >> 4;
  const int wr = wid >> 2, wc = wid & 3;
  const int m0 = blockIdx.y * BM, n0 = blockIdx.x * 256;

  // staging: lane supplies row chunkbase + (lane>>2), src col pre-XORed
  const int srl = lane >> 2;
  const int scb = ((lane & 3) << 4) ^ (((lane >> 3) & 3) << 4);
  const int rk  = ((l15 >> 1) & 3) << 4;  // read-side XOR key
  const size_t Krow = (size_t)K * 2;      // row bytes

  auto stageA = [&](int b, int kh, int t) {
#pragma unroll
    for (int L = 0; L < GA; ++L) {
      const char* src = (const char*)A + (size_t)(m0 + L * 128 + wid * 16 + srl) * Krow
                        + (size_t)t * 128 + kh * 64 + scb;
      glds16(src, (char*)aL + (size_t)((b * 2 + kh) * BM + L * 128 + wid * 16) * 64);
    }
  };
  auto stageB = [&](int b, int kh, int t) {
#pragma unroll
    for (int L = 0; L < 2; ++L) {
      const char* src = (const char*)Bt + (size_t)(n0 + L * 128 + wid * 16 + srl) * Krow
                        + (size_t)t * 128 + kh * 64 + scb;
      glds16(src, (char*)bL + (size_t)((b * 2 + kh) * 256 + L * 128 + wid * 16) * 64);
    }
  };

  bf16x8 af[MF], bfr[4];
  f32x4 acc[MF][4] = {};

  auto loadA = [&](int b, int kh) {
#pragma unroll
    for (int m = 0; m < MF; ++m)
      af[m] = *(const bf16x8*)((const char*)aL +
          (size_t)((b * 2 + kh) * BM + wr * (BM / 2) + m * 16 + l15) * 64 + ((g * 16) ^ rk));
  };
  auto loadB = [&](int b, int kh, int nh) {
#pragma unroll
    for (int n = 0; n < 2; ++n)
      bfr[nh * 2 + n] = *(const bf16x8*)((const char*)bL +
          (size_t)((b * 2 + kh) * 256 + wc * 64 + (nh * 2 + n) * 16 + l15) * 64 + ((g * 16) ^ rk));
  };
  auto mfma8 = [&](int nh) {
    __builtin_amdgcn_s_setprio(1);
#pragma unroll
    for (int m = 0; m < MF; ++m) {
      acc[m][nh * 2]     = __builtin_amdgcn_mfma_f32_16x16x32_bf16(af[m], bfr[nh * 2],     acc[m][nh * 2],     0, 0, 0);
      acc[m][nh * 2 + 1] = __builtin_amdgcn_mfma_f32_16x16x32_bf16(af[m], bfr[nh * 2 + 1], acc[m][nh * 2 + 1], 0, 0, 0);
    }
    __builtin_amdgcn_s_setprio(0);
  };

  // prologue: stage tile 0 (issue order: A.k0, B.k0, A.k1, B.k1)
  stageA(0, 0, 0); stageB(0, 0, 0); stageA(0, 1, 0); stageB(0, 1, 0);
  if constexpr (MF == 8) { WAITVM(4); } else { WAITVM(3); }
  barx();

  const int nk = K >> 6;
  int cur = 0;
  for (int t = 0; t < nk; ++t) {
    const bool pf = (t + 1 < nk);
    const int nb = cur ^ 1;
    // ---- P0 : kk0, n-half 0
    loadA(cur, 0); loadB(cur, 0, 0);
    if (pf) stageA(nb, 0, t + 1);
    barx();
    mfma8(0);
    barx();
    // ---- P1 : kk0, n-half 1
    loadB(cur, 0, 1);
    if (pf) stageB(nb, 0, t + 1);
    barx();
    mfma8(1);
    if (pf) { if constexpr (MF == 8) { WAITVM(4); } else { WAITVM(3); } }
    else    { WAITVM(0); }
    barx();
    // ---- P2 : kk1, n-half 0
    loadA(cur, 1); loadB(cur, 1, 0);
    if (pf) stageA(nb, 1, t + 1);
    barx();
    mfma8(0);
    barx();
    // ---- P3 : kk1, n-half 1
    loadB(cur, 1, 1);
    if (pf) stageB(nb, 1, t + 1);
    barx();
    mfma8(1);
    if (pf) { if constexpr (MF == 8) { WAITVM(4); } else { WAITVM(3); } }
    barx();
    cur = nb;
  }

  const int rb = m0 + wr * (BM / 2);
  const int cb = n0 + wc * 64;
  if constexpr (EPI == 0) {
    // QKV: c = which*1024 + h*64 + dd ; rope pairs (dd, dd+32) live in frags (n, n+2)
#pragma unroll
    for (int m = 0; m < MF; ++m)
#pragma unroll
      for (int r = 0; r < 4; ++r) {
        const int s = rb + m * 16 + g * 4 + r;
        const int bb = s >> 11, ii = s & 2047;
#pragma unroll
        for (int n = 0; n < 2; ++n) {
          const int c = cb + n * 16 + l15;
          const int which = c >> 10, h = (c >> 6) & 15, dd = c & 63;  // dd < 32
          const float vlo = acc[m][n][r] + bias[c];
          const float vhi = acc[m][n + 2][r] + bias[c + 32];
          const size_t off = ((size_t)((bb * 16 + h) * 2048 + ii)) * 64;
          if (which == 2) {
            vo[off + dd]      = f2bf(vlo);
            vo[off + dd + 32] = f2bf(vhi);
          } else {
            const float fr = __expf(-0.29710776f * (float)dd);  // 10000^(-dd/31)
            const float ang = (float)ii * fr;
            const float c0 = cosf(ang), s0 = sinf(ang);
            float rlo = vlo * c0 - vhi * s0;
            float rhi = vhi * c0 + vlo * s0;
            if (which == 0) { rlo *= 0.125f; rhi *= 0.125f; }  // fold attn scale into Q
            ushort* dst = (which == 0) ? qo : ko;
            dst[off + dd]      = f2bf(rlo);
            dst[off + dd + 32] = f2bf(rhi);
          }
        }
      }
  } else {
#pragma unroll
    for (int m = 0; m < MF; ++m)
#pragma unroll
      for (int n = 0; n < 4; ++n)
#pragma unroll
        for (int r = 0; r < 4; ++r) {
          const int row = rb + m * 16 + g * 4 + r;
          const int col = cb + n * 16 + l15;
          float v = acc[m][n][r] + bias[col];
          if constexpr (EPI == 1) {
            v += resid[(size_t)row * N + col];
            outf[(size_t)row * N + col] = v;
          } else {
            const float ge = 0.5f * v * (1.0f + erff(v * 0.70710678f));
            outb[(size_t)row * N + col] = f2bf(ge);
          }
        }
  }
}

// ---------------------------------------------------------------- flash attention, swapped-QK^T, v5 (unchanged)
__global__ __launch_bounds__(256) void attn_k(const ushort* __restrict__ Q,
                                              const ushort* __restrict__ K,
                                              const ushort* __restrict__ Vt,
                                              ushort* __restrict__ O) {
  const int bh = blockIdx.x;
  const int qt = 31 - blockIdx.y;      // LPT: heavy (large qt) blocks first
  const int tid = threadIdx.x, wid = tid >> 6, lane = tid & 63;
  const int l15 = lane & 15, g = lane >> 4;
  const size_t bho = (size_t)bh * (2048 * 64);
  const ushort* Qb = Q + bho;
  const char*   KbB = (const char*)(K + bho);   // byte base, row stride 128B
  const char*   VbB = (const char*)(Vt + bho);  // byte base, row stride 4096B
  const int b = bh >> 4, h = bh & 15;

  __shared__ ushort kl[2][64 * 64];   // K tile [64 k][64 d], swizzled
  __shared__ ushort vl[2][64 * 64];   // V tile [64 d][64 k], swizzled
  __shared__ ushort pl[4][16 * 64];   // per-wave P tile [16 q][64 k], swizzled

  const int rbase = wid * 16;
  const int rsub  = lane >> 3;               // 0..7
  const int cbyte = (lane & 7) << 4;         // dest byte col 0..112
  const int scb   = cbyte ^ (rsub << 4);     // pre-swizzled source byte col

  const int q0 = qt * 64 + wid * 16;

  const bf16x8 qf0 = *(const bf16x8*)&Qb[(size_t)(q0 + l15) * 64 + g * 8];
  const bf16x8 qf1 = *(const bf16x8*)&Qb[(size_t)(q0 + l15) * 64 + 32 + g * 8];

  f32x4 o[4] = {};
  float m = -1e30f, l = 0.f;

  char* pbase = (char*)pl[wid];
  const int swz  = (l15 & 7) << 4;
  const int skey = (l15 & 7) << 4;

  const int nkt = qt + 1;
  {
    const char* ks0 = KbB + (size_t)(0 + rbase + rsub) * 128 + scb;
    const char* vs0 = VbB + (size_t)(rbase + rsub) * 4096 + scb;
    glds16(ks0,            (char*)kl[0] + rbase * 128);
    glds16(ks0 + 8 * 128,  (char*)kl[0] + (rbase + 8) * 128);
    glds16(vs0,            (char*)vl[0] + rbase * 128);
    glds16(vs0 + 8 * 4096, (char*)vl[0] + (rbase + 8) * 128);
  }
  int cur = 0;

  for (int kt = 0; kt < nkt; ++kt) {
    const int k0 = kt * 64;
    __syncthreads();
    if (kt + 1 < nkt) {
      const int nb = cur ^ 1, k1 = k0 + 64;
      const char* ks0 = KbB + (size_t)(k1 + rbase + rsub) * 128 + scb;
      const char* vs0 = VbB + (size_t)(rbase + rsub) * 4096 + (size_t)k1 * 2 + scb;
      glds16(ks0,            (char*)kl[nb] + rbase * 128);
      glds16(ks0 + 8 * 128,  (char*)kl[nb] + (rbase + 8) * 128);
      glds16(vs0,            (char*)vl[nb] + rbase * 128);
      glds16(vs0 + 8 * 4096, (char*)vl[nb] + (rbase + 8) * 128);
    }
    const char* Klds = (const char*)kl[cur];
    const char* Vlds = (const char*)vl[cur];

    f32x4 st[4];
    __builtin_amdgcn_s_setprio(1);
#pragma unroll
    for (int sub = 0; sub < 4; ++sub) {
      const int kr = sub * 16 + l15;
      const bf16x8 kf0 = *(const bf16x8*)(Klds + kr * 128 + ((g * 16) ^ skey));
      const bf16x8 kf1 = *(const bf16x8*)(Klds + kr * 128 + ((64 + g * 16) ^ skey));
      f32x4 z = {0.f, 0.f, 0.f, 0.f};
      f32x4 sv = __builtin_amdgcn_mfma_f32_16x16x32_bf16(kf0, qf0, z, 0, 0, 0);
      sv = __builtin_amdgcn_mfma_f32_16x16x32_bf16(kf1, qf1, sv, 0, 0, 0);
      st[sub] = sv;
    }
    __builtin_amdgcn_s_setprio(0);
    if (k0 + 63 > q0) {
#pragma unroll
      for (int sub = 0; sub < 4; ++sub) {
        const int kk = k0 + sub * 16 + g * 4;
#pragma unroll
        for (int r = 0; r < 4; ++r)
          if (kk + r > q0 + l15) st[sub][r] = -1e30f;
      }
    }
    f32x4 mv = st[0];
#pragma unroll
    for (int sub = 1; sub < 4; ++sub)
#pragma unroll
      for (int r = 0; r < 4; ++r) mv[r] = fmaxf(mv[r], st[sub][r]);
    float tm = fmaxf(fmaxf(mv[0], mv[1]), fmaxf(mv[2], mv[3]));
    tm = fmaxf(tm, __shfl_xor(tm, 16));
    tm = fmaxf(tm, __shfl_xor(tm, 32));
    if (!__all(tm - m <= 8.0f)) {
      const float mnew = fmaxf(m, tm);
      const float corr = __expf(m - mnew);
      m = mnew;
      l *= corr;
      float cr[4];
#pragma unroll
      for (int r = 0; r < 4; ++r) cr[r] = __shfl(corr, g * 4 + r);
#pragma unroll
      for (int nf = 0; nf < 4; ++nf)
#pragma unroll
        for (int r = 0; r < 4; ++r) o[nf][r] *= cr[r];
    }
    float ps = 0.f;
#pragma unroll
    for (int sub = 0; sub < 4; ++sub) {
      const float p0 = __expf(st[sub][0] - m);
      const float p1 = __expf(st[sub][1] - m);
      const float p2 = __expf(st[sub][2] - m);
      const float p3 = __expf(st[sub][3] - m);
      ps += (p0 + p1) + (p2 + p3);
      ushort4 pk;
      pk.x = f2bf(p0); pk.y = f2bf(p1); pk.z = f2bf(p2); pk.w = f2bf(p3);
      *(ushort4*)(pbase + ((l15 * 128 + ((sub * 32 + g * 8) ^ swz)))) = pk;
    }
    ps += __shfl_xor(ps, 16);
    ps += __shfl_xor(ps, 32);
    l += ps;
    const bf16x8 pf0 = *(const bf16x8*)(pbase + (l15 * 128 + ((g * 16) ^ swz)));
    const bf16x8 pf1 = *(const bf16x8*)(pbase + (l15 * 128 + ((64 + g * 16) ^ swz)));
    __builtin_amdgcn_s_setprio(1);
#pragma unroll
    for (int nf = 0; nf < 4; ++nf) {
      const int dr = nf * 16 + l15;
      const bf16x8 vf0 = *(const bf16x8*)(Vlds + dr * 128 + ((g * 16) ^ skey));
      const bf16x8 vf1 = *(const bf16x8*)(Vlds + dr * 128 + ((64 + g * 16) ^ skey));
      o[nf] = __builtin_amdgcn_mfma_f32_16x16x32_bf16(pf0, vf0, o[nf], 0, 0, 0);
      o[nf] = __builtin_amdgcn_mfma_f32_16x16x32_bf16(pf1, vf1, o[nf], 0, 0, 0);
    }
    __builtin_amdgcn_s_setprio(0);
    cur ^= 1;
  }
  const float linv = 1.0f / l;
  float li[4];
#pragma unroll
  for (int r = 0; r < 4; ++r) li[r] = __shfl(linv, g * 4 + r);
#pragma unroll
  for (int nf = 0; nf < 4; ++nf)
#pragma unroll
    for (int r = 0; r < 4; ++r) {
      const int qr = q0 + g * 4 + r;
      O[((size_t)(b * 2048 + qr)) * 1024 + h * 64 + nf * 16 + l15] = f2bf(o[nf][r] * li[r]);
    }
}

// ---------------------------------------------------------------- launcher
extern "C" void kernel_launch(void* const* d_in, const int* in_sizes, int n_in,
                              void* d_out, int out_size, void* d_ws, size_t ws_size,
                              hipStream_t stream) {
  const float* x      = (const float*)d_in[0];
  const float* w_qkv  = (const float*)d_in[2];
  const float* b_qkv  = (const float*)d_in[3];
  const float* w_proj = (const float*)d_in[4];
  const float* b_proj = (const float*)d_in[5];
  const float* g1     = (const float*)d_in[6];
  const float* be1    = (const float*)d_in[7];
  const float* g2     = (const float*)d_in[8];
  const float* be2    = (const float*)d_in[9];
  const float* w_mlp1 = (const float*)d_in[10];
  const float* b_mlp1 = (const float*)d_in[11];
  const float* w_mlp2 = (const float*)d_in[12];
  const float* b_mlp2 = (const float*)d_in[13];

  char* ws = (char*)d_ws;
  ushort* WQKVT  = (ushort*)(ws + 0);
  ushort* WPROJT = (ushort*)(ws + 6291456);
  ushort* WMLP1T = (ushort*)(ws + 8388608);
  ushort* WMLP2T = (ushort*)(ws + 16777216);
  ushort* H      = (ushort*)(ws + 25165824);
  ushort* Qs     = (ushort*)(ws + 41943040);
  ushort* Ks     = (ushort*)(ws + 58720256);
  ushort* Vn     = (ushort*)(ws + 75497472);
  ushort* Vt     = (ushort*)(ws + 92274688);
  ushort* M1     = (ushort*)(ws + 41943040);
  float*  X1     = (float*)(ws + 109051904);

  // allow >64KB dynamic LDS (idempotent; host-side, capture-safe)
  hipFuncSetAttribute((const void*)gemm2_k<8, 0>, hipFuncAttributeMaxDynamicSharedMemorySize, 131072);
  hipFuncSetAttribute((const void*)gemm2_k<8, 2>, hipFuncAttributeMaxDynamicSharedMemorySize, 131072);
  hipFuncSetAttribute((const void*)gemm2_k<4, 1>, hipFuncAttributeMaxDynamicSharedMemorySize, 98304);

  castT_k<<<dim3(3072 / 32, 1024 / 32), 256, 0, stream>>>(w_qkv, WQKVT, 1024, 3072);
  castT_k<<<dim3(1024 / 32, 1024 / 32), 256, 0, stream>>>(w_proj, WPROJT, 1024, 1024);
  castT_k<<<dim3(4096 / 32, 1024 / 32), 256, 0, stream>>>(w_mlp1, WMLP1T, 1024, 4096);
  castT_k<<<dim3(1024 / 32, 4096 / 32), 256, 0, stream>>>(w_mlp2, WMLP2T, 4096, 1024);

  ln_k<<<8192, 256, 0, stream>>>(x, g1, be1, H);

  gemm2_k<8, 0><<<dim3(3072 / 256, 8192 / 256), 512, 131072, stream>>>(
      H, WQKVT, 8192, 3072, 1024, b_qkv, nullptr, nullptr, nullptr, Qs, Ks, Vn);

  vtrans_k<<<dim3(32, 64), 256, 0, stream>>>(Vn, Vt);

  attn_k<<<dim3(64, 32), 256, 0, stream>>>(Qs, Ks, Vt, H /* = O */);

  gemm2_k<4, 1><<<dim3(1024 / 256, 8192 / 128), 512, 98304, stream>>>(
      H, WPROJT, 8192, 1024, 1024, b_proj, x, X1, nullptr, nullptr, nullptr, nullptr);

  ln_k<<<8192, 256, 0, stream>>>(X1, g2, be2, H /* = H2 */);

  gemm2_k<8, 2><<<dim3(4096 / 256, 8192 / 256), 512, 131072, stream>>>(
      H, WMLP1T, 8192, 4096, 1024, b_mlp1, nullptr, nullptr, M1, nullptr, nullptr, nullptr);

  gemm2_k<4, 1><<<dim3(1024 / 256, 8192 / 128), 512, 98304, stream>>>(
      M1, WMLP2T, 8192, 1024, 4096, b_mlp2, X1, (float*)d_out, nullptr, nullptr, nullptr, nullptr);
}

// Round 8
// 567.962 us; speedup vs baseline: 1.0570x; 1.0570x over previous
//
#include <hip/hip_runtime.h>

// ---------------------------------------------------------------- types
typedef __bf16  bf16x8 __attribute__((ext_vector_type(8)));
typedef float   f32x4  __attribute__((ext_vector_type(4)));

typedef const __attribute__((address_space(1))) void* gas_p;
typedef __attribute__((address_space(3))) void*       las_p;

__device__ __forceinline__ void glds16(const void* g, void* l) {
  // global -> LDS direct, 16B per lane; LDS dst is wave-uniform base + lane*16
  __builtin_amdgcn_global_load_lds((gas_p)g, (las_p)l, 16, 0, 0);
}

__device__ __forceinline__ ushort f2bf(float f) {  // RNE float->bf16
  unsigned u = __float_as_uint(f);
  u += 0x7fffu + ((u >> 16) & 1u);
  return (ushort)(u >> 16);
}

__device__ __forceinline__ void barx() {  // raw barrier w/ compiler memory fences
  asm volatile("" ::: "memory");
  __builtin_amdgcn_s_barrier();
  asm volatile("" ::: "memory");
}
#define WAITVM(N) asm volatile("s_waitcnt vmcnt(" #N ")" ::: "memory")

__device__ __forceinline__ float erf_fast(float x) {  // A&S 7.1.26, |eps|<=1.5e-7
  const float ax = fabsf(x);
  const float t = __frcp_rn(1.0f + 0.3275911f * ax);
  float p = 1.061405429f;
  p = p * t - 1.453152027f;
  p = p * t + 1.421413741f;
  p = p * t - 0.284496736f;
  p = p * t + 0.254829592f;
  const float y = 1.0f - p * t * __expf(-ax * ax);
  return copysignf(y, x);
}

// ---------------------------------------------------------------- weight cast + transpose  w[K][N] f32 -> wT[N][K] bf16
__global__ __launch_bounds__(256) void castT_k(const float* __restrict__ w,
                                               ushort* __restrict__ wT,
                                               const int Kd, const int Nd) {
  __shared__ float t[32][33];
  const int nb = blockIdx.x * 32, kb = blockIdx.y * 32;
  const int tx = threadIdx.x & 31, ty = threadIdx.x >> 5;  // 32 x 8
#pragma unroll
  for (int r = 0; r < 32; r += 8)
    t[ty + r][tx] = w[(size_t)(kb + ty + r) * Nd + nb + tx];
  __syncthreads();
#pragma unroll
  for (int r = 0; r < 32; r += 8)
    wT[(size_t)(nb + ty + r) * Kd + kb + tx] = f2bf(t[tx][ty + r]);
}

// ---------------------------------------------------------------- LayerNorm (d=1024), fp32 in -> bf16 out
__global__ __launch_bounds__(256) void ln_k(const float* __restrict__ x,
                                            const float* __restrict__ gam,
                                            const float* __restrict__ bet,
                                            ushort* __restrict__ out) {
  const int row = blockIdx.x, tid = threadIdx.x;
  const float4 v = ((const float4*)(x + (size_t)row * 1024))[tid];
  float s  = v.x + v.y + v.z + v.w;
  float sq = v.x * v.x + v.y * v.y + v.z * v.z + v.w * v.w;
#pragma unroll
  for (int o = 32; o > 0; o >>= 1) { s += __shfl_xor(s, o); sq += __shfl_xor(sq, o); }
  __shared__ float red[8];
  const int wid = tid >> 6, lane = tid & 63;
  if (lane == 0) { red[wid] = s; red[4 + wid] = sq; }
  __syncthreads();
  s  = red[0] + red[1] + red[2] + red[3];
  sq = red[4] + red[5] + red[6] + red[7];
  const float mu   = s * (1.0f / 1024.0f);
  const float var  = sq * (1.0f / 1024.0f) - mu * mu;
  const float rstd = rsqrtf(var + 1e-5f);
  const float4 gv = ((const float4*)gam)[tid];
  const float4 bv = ((const float4*)bet)[tid];
  ushort4 o4;
  o4.x = f2bf((v.x - mu) * rstd * gv.x + bv.x);
  o4.y = f2bf((v.y - mu) * rstd * gv.y + bv.y);
  o4.z = f2bf((v.z - mu) * rstd * gv.z + bv.z);
  o4.w = f2bf((v.w - mu) * rstd * gv.w + bv.w);
  ((ushort4*)(out + (size_t)row * 1024))[tid] = o4;
}

// ---------------------------------------------------------------- V [B,H,T,64] -> Vt [B,H,64,T]  (bf16)
__global__ __launch_bounds__(256) void vtrans_k(const ushort* __restrict__ Vn,
                                                ushort* __restrict__ Vt) {
  const int bh = blockIdx.y, i0 = blockIdx.x * 64, tid = threadIdx.x;
  __shared__ ushort t[64][65];
  const ushort* src = Vn + (size_t)bh * (2048 * 64);
#pragma unroll
  for (int kk = 0; kk < 16; ++kk) {
    const int e = tid + kk * 256, r = e >> 6, c = e & 63;
    t[r][c] = src[(size_t)(i0 + r) * 64 + c];
  }
  __syncthreads();
  ushort* dst = Vt + (size_t)bh * (64 * 2048);
#pragma unroll
  for (int kk = 0; kk < 16; ++kk) {
    const int e = tid + kk * 256, r = e >> 6, c = e & 63;  // r = dh, c = i
    dst[(size_t)r * 2048 + i0 + c] = t[c][r];
  }
}

// ---------------------------------------------------------------- GEMM v3: 3-deep pipeline, BK=32, 8 waves
// A[M][K] x Bt[N][K] bf16. BM = 32*MF (256 / 128), BN = 256. Per-wave C: (MF*16) x 64.
// THREE LDS buffers; stage tile t+2 at top of tile t -> prefetch distance ~2 K-tile
// bodies (~800+cy, covers L3/HBM miss latency). ONE barrier + ONE counted WAITVM per
// K-tile: per-wave drain own stages (4 or 3 calls) then barrier publishes all waves'.
// Buf safety: stage(t+2) targets buf (t+2)%3 whose last reads were in iter t-1,
// separated by iter t's barrier. T2 swizzle: 64B rows allow 4-way max (accepted);
// write-side pre-swizzled global src col, read-side ((l15&3)<<4) XOR.
// T1: bijective XCD swizzle on flat block id (all grids %8 == 0).
template <int MF, int EPI>
__global__ __launch_bounds__(512, 2) void gemm3_k(
    const ushort* __restrict__ A, const ushort* __restrict__ Bt,
    const int M, const int N, const int K,
    const float* __restrict__ bias,
    const float* __restrict__ resid,
    float* __restrict__ outf,
    ushort* __restrict__ outb,
    ushort* __restrict__ qo, ushort* __restrict__ ko, ushort* __restrict__ vo) {
  constexpr int BM = MF * 32;
  constexpr int ACALLS = MF / 4;       // A stage calls per wave (2 or 1)
  extern __shared__ ushort lds_u[];
  ushort* aL = lds_u;                  // [3][BM][32]
  ushort* bL = lds_u + 3 * BM * 32;    // [3][256][32]

  const int tid = threadIdx.x, wid = tid >> 6, lane = tid & 63;
  const int l15 = lane & 15, g = lane >> 4;
  const int wr = wid >> 2, wc = wid & 3;

  // T1: XCD-aware bijective remap (chunk nwg/8 consecutive tiles per XCD)
  const int gx = gridDim.x, nwg = gx * gridDim.y;
  const int f = blockIdx.y * gx + blockIdx.x;
  const int swz = (f & 7) * (nwg >> 3) + (f >> 3);
  const int m0 = (swz / gx) * BM, n0 = (swz % gx) * 256;

  const int srl = lane >> 2;                              // row within 16-row chunk
  const int scb = ((lane & 3) << 4) ^ ((srl & 3) << 4);   // pre-swizzled src col byte
  const int rk  = (l15 & 3) << 4;                         // read-side XOR key
  const size_t Krow = (size_t)K * 2;

  auto stageA = [&](int buf, int t) {
#pragma unroll
    for (int L = 0; L < ACALLS; ++L) {
      const int base = (wid * ACALLS + L) * 16;
      glds16((const char*)A + (size_t)(m0 + base + srl) * Krow + (size_t)t * 64 + scb,
             (char*)aL + (size_t)(buf * BM + base) * 64);
    }
  };
  auto stageB = [&](int buf, int t) {
#pragma unroll
    for (int L = 0; L < 2; ++L) {
      const int base = (wid * 2 + L) * 16;
      glds16((const char*)Bt + (size_t)(n0 + base + srl) * Krow + (size_t)t * 64 + scb,
             (char*)bL + (size_t)(buf * 256 + base) * 64);
    }
  };

  f32x4 acc[MF][4] = {};

  // prologue: stage tiles 0 and 1
  stageA(0, 0); stageB(0, 0);
  stageA(1, 1); stageB(1, 1);

  const int nk = K >> 5;
  int b0 = 0;  // buffer holding tile t
  for (int t = 0; t < nk; ++t) {
    if (t + 2 < nk) {
      if constexpr (MF == 8) { WAITVM(4); } else { WAITVM(3); }
    } else {
      WAITVM(0);
    }
    barx();  // per-wave drain + barrier => all waves' tile-t stages visible
    if (t + 2 < nk) {
      int nbuf = b0 + 2; if (nbuf >= 3) nbuf -= 3;
      stageA(nbuf, t + 2); stageB(nbuf, t + 2);
    }
    bf16x8 af[MF], bfr[4];
#pragma unroll
    for (int m = 0; m < MF; ++m)
      af[m] = *(const bf16x8*)((const char*)aL +
          (size_t)(b0 * BM + wr * (BM / 2) + m * 16 + l15) * 64 + ((g * 16) ^ rk));
#pragma unroll
    for (int n = 0; n < 4; ++n)
      bfr[n] = *(const bf16x8*)((const char*)bL +
          (size_t)(b0 * 256 + wc * 64 + n * 16 + l15) * 64 + ((g * 16) ^ rk));
    __builtin_amdgcn_s_setprio(1);
#pragma unroll
    for (int m = 0; m < MF; ++m)
#pragma unroll
      for (int n = 0; n < 4; ++n)
        acc[m][n] = __builtin_amdgcn_mfma_f32_16x16x32_bf16(af[m], bfr[n], acc[m][n], 0, 0, 0);
    __builtin_amdgcn_s_setprio(0);
    ++b0; if (b0 == 3) b0 = 0;
  }

  const int rb = m0 + wr * (BM / 2);
  const int cb = n0 + wc * 64;
  if constexpr (EPI == 0) {
    // QKV: c = which*1024 + h*64 + dd ; rope pairs (dd, dd+32) live in frags (n, n+2)
#pragma unroll
    for (int m = 0; m < MF; ++m)
#pragma unroll
      for (int r = 0; r < 4; ++r) {
        const int s = rb + m * 16 + g * 4 + r;
        const int bb = s >> 11, ii = s & 2047;
#pragma unroll
        for (int n = 0; n < 2; ++n) {
          const int c = cb + n * 16 + l15;
          const int which = c >> 10, h = (c >> 6) & 15, dd = c & 63;  // dd < 32
          const float vlo = acc[m][n][r] + bias[c];
          const float vhi = acc[m][n + 2][r] + bias[c + 32];
          const size_t off = ((size_t)((bb * 16 + h) * 2048 + ii)) * 64;
          if (which == 2) {
            vo[off + dd]      = f2bf(vlo);
            vo[off + dd + 32] = f2bf(vhi);
          } else {
            const float fr = __expf(-0.29710776f * (float)dd);  // 10000^(-dd/31)
            const float ang = (float)ii * fr;
            const float c0 = cosf(ang), s0 = sinf(ang);
            float rlo = vlo * c0 - vhi * s0;
            float rhi = vhi * c0 + vlo * s0;
            if (which == 0) { rlo *= 0.125f; rhi *= 0.125f; }  // fold attn scale into Q
            ushort* dst = (which == 0) ? qo : ko;
            dst[off + dd]      = f2bf(rlo);
            dst[off + dd + 32] = f2bf(rhi);
          }
        }
      }
  } else {
#pragma unroll
    for (int m = 0; m < MF; ++m)
#pragma unroll
      for (int n = 0; n < 4; ++n)
#pragma unroll
        for (int r = 0; r < 4; ++r) {
          const int row = rb + m * 16 + g * 4 + r;
          const int col = cb + n * 16 + l15;
          float v = acc[m][n][r] + bias[col];
          if constexpr (EPI == 1) {
            v += resid[(size_t)row * N + col];
            outf[(size_t)row * N + col] = v;
          } else {
            const float ge = 0.5f * v * (1.0f + erf_fast(v * 0.70710678f));
            outb[(size_t)row * N + col] = f2bf(ge);
          }
        }
  }
}

// ---------------------------------------------------------------- flash attention, swapped-QK^T, v5 (unchanged)
__global__ __launch_bounds__(256) void attn_k(const ushort* __restrict__ Q,
                                              const ushort* __restrict__ K,
                                              const ushort* __restrict__ Vt,
                                              ushort* __restrict__ O) {
  const int bh = blockIdx.x;
  const int qt = 31 - blockIdx.y;      // LPT: heavy (large qt) blocks first
  const int tid = threadIdx.x, wid = tid >> 6, lane = tid & 63;
  const int l15 = lane & 15, g = lane >> 4;
  const size_t bho = (size_t)bh * (2048 * 64);
  const ushort* Qb = Q + bho;
  const char*   KbB = (const char*)(K + bho);   // byte base, row stride 128B
  const char*   VbB = (const char*)(Vt + bho);  // byte base, row stride 4096B
  const int b = bh >> 4, h = bh & 15;

  __shared__ ushort kl[2][64 * 64];   // K tile [64 k][64 d], swizzled
  __shared__ ushort vl[2][64 * 64];   // V tile [64 d][64 k], swizzled
  __shared__ ushort pl[4][16 * 64];   // per-wave P tile [16 q][64 k], swizzled

  const int rbase = wid * 16;
  const int rsub  = lane >> 3;               // 0..7
  const int cbyte = (lane & 7) << 4;         // dest byte col 0..112
  const int scb   = cbyte ^ (rsub << 4);     // pre-swizzled source byte col

  const int q0 = qt * 64 + wid * 16;

  const bf16x8 qf0 = *(const bf16x8*)&Qb[(size_t)(q0 + l15) * 64 + g * 8];
  const bf16x8 qf1 = *(const bf16x8*)&Qb[(size_t)(q0 + l15) * 64 + 32 + g * 8];

  f32x4 o[4] = {};
  float m = -1e30f, l = 0.f;

  char* pbase = (char*)pl[wid];
  const int swz  = (l15 & 7) << 4;
  const int skey = (l15 & 7) << 4;

  const int nkt = qt + 1;
  {
    const char* ks0 = KbB + (size_t)(0 + rbase + rsub) * 128 + scb;
    const char* vs0 = VbB + (size_t)(rbase + rsub) * 4096 + scb;
    glds16(ks0,            (char*)kl[0] + rbase * 128);
    glds16(ks0 + 8 * 128,  (char*)kl[0] + (rbase + 8) * 128);
    glds16(vs0,            (char*)vl[0] + rbase * 128);
    glds16(vs0 + 8 * 4096, (char*)vl[0] + (rbase + 8) * 128);
  }
  int cur = 0;

  for (int kt = 0; kt < nkt; ++kt) {
    const int k0 = kt * 64;
    __syncthreads();
    if (kt + 1 < nkt) {
      const int nb = cur ^ 1, k1 = k0 + 64;
      const char* ks0 = KbB + (size_t)(k1 + rbase + rsub) * 128 + scb;
      const char* vs0 = VbB + (size_t)(rbase + rsub) * 4096 + (size_t)k1 * 2 + scb;
      glds16(ks0,            (char*)kl[nb] + rbase * 128);
      glds16(ks0 + 8 * 128,  (char*)kl[nb] + (rbase + 8) * 128);
      glds16(vs0,            (char*)vl[nb] + rbase * 128);
      glds16(vs0 + 8 * 4096, (char*)vl[nb] + (rbase + 8) * 128);
    }
    const char* Klds = (const char*)kl[cur];
    const char* Vlds = (const char*)vl[cur];

    f32x4 st[4];
    __builtin_amdgcn_s_setprio(1);
#pragma unroll
    for (int sub = 0; sub < 4; ++sub) {
      const int kr = sub * 16 + l15;
      const bf16x8 kf0 = *(const bf16x8*)(Klds + kr * 128 + ((g * 16) ^ skey));
      const bf16x8 kf1 = *(const bf16x8*)(Klds + kr * 128 + ((64 + g * 16) ^ skey));
      f32x4 z = {0.f, 0.f, 0.f, 0.f};
      f32x4 sv = __builtin_amdgcn_mfma_f32_16x16x32_bf16(kf0, qf0, z, 0, 0, 0);
      sv = __builtin_amdgcn_mfma_f32_16x16x32_bf16(kf1, qf1, sv, 0, 0, 0);
      st[sub] = sv;
    }
    __builtin_amdgcn_s_setprio(0);
    if (k0 + 63 > q0) {
#pragma unroll
      for (int sub = 0; sub < 4; ++sub) {
        const int kk = k0 + sub * 16 + g * 4;
#pragma unroll
        for (int r = 0; r < 4; ++r)
          if (kk + r > q0 + l15) st[sub][r] = -1e30f;
      }
    }
    f32x4 mv = st[0];
#pragma unroll
    for (int sub = 1; sub < 4; ++sub)
#pragma unroll
      for (int r = 0; r < 4; ++r) mv[r] = fmaxf(mv[r], st[sub][r]);
    float tm = fmaxf(fmaxf(mv[0], mv[1]), fmaxf(mv[2], mv[3]));
    tm = fmaxf(tm, __shfl_xor(tm, 16));
    tm = fmaxf(tm, __shfl_xor(tm, 32));
    if (!__all(tm - m <= 8.0f)) {
      const float mnew = fmaxf(m, tm);
      const float corr = __expf(m - mnew);
      m = mnew;
      l *= corr;
      float cr[4];
#pragma unroll
      for (int r = 0; r < 4; ++r) cr[r] = __shfl(corr, g * 4 + r);
#pragma unroll
      for (int nf = 0; nf < 4; ++nf)
#pragma unroll
        for (int r = 0; r < 4; ++r) o[nf][r] *= cr[r];
    }
    float ps = 0.f;
#pragma unroll
    for (int sub = 0; sub < 4; ++sub) {
      const float p0 = __expf(st[sub][0] - m);
      const float p1 = __expf(st[sub][1] - m);
      const float p2 = __expf(st[sub][2] - m);
      const float p3 = __expf(st[sub][3] - m);
      ps += (p0 + p1) + (p2 + p3);
      ushort4 pk;
      pk.x = f2bf(p0); pk.y = f2bf(p1); pk.z = f2bf(p2); pk.w = f2bf(p3);
      *(ushort4*)(pbase + ((l15 * 128 + ((sub * 32 + g * 8) ^ swz)))) = pk;
    }
    ps += __shfl_xor(ps, 16);
    ps += __shfl_xor(ps, 32);
    l += ps;
    const bf16x8 pf0 = *(const bf16x8*)(pbase + (l15 * 128 + ((g * 16) ^ swz)));
    const bf16x8 pf1 = *(const bf16x8*)(pbase + (l15 * 128 + ((64 + g * 16) ^ swz)));
    __builtin_amdgcn_s_setprio(1);
#pragma unroll
    for (int nf = 0; nf < 4; ++nf) {
      const int dr = nf * 16 + l15;
      const bf16x8 vf0 = *(const bf16x8*)(Vlds + dr * 128 + ((g * 16) ^ skey));
      const bf16x8 vf1 = *(const bf16x8*)(Vlds + dr * 128 + ((64 + g * 16) ^ skey));
      o[nf] = __builtin_amdgcn_mfma_f32_16x16x32_bf16(pf0, vf0, o[nf], 0, 0, 0);
      o[nf] = __builtin_amdgcn_mfma_f32_16x16x32_bf16(pf1, vf1, o[nf], 0, 0, 0);
    }
    __builtin_amdgcn_s_setprio(0);
    cur ^= 1;
  }
  const float linv = 1.0f / l;
  float li[4];
#pragma unroll
  for (int r = 0; r < 4; ++r) li[r] = __shfl(linv, g * 4 + r);
#pragma unroll
  for (int nf = 0; nf < 4; ++nf)
#pragma unroll
    for (int r = 0; r < 4; ++r) {
      const int qr = q0 + g * 4 + r;
      O[((size_t)(b * 2048 + qr)) * 1024 + h * 64 + nf * 16 + l15] = f2bf(o[nf][r] * li[r]);
    }
}

// ---------------------------------------------------------------- launcher
extern "C" void kernel_launch(void* const* d_in, const int* in_sizes, int n_in,
                              void* d_out, int out_size, void* d_ws, size_t ws_size,
                              hipStream_t stream) {
  const float* x      = (const float*)d_in[0];
  const float* w_qkv  = (const float*)d_in[2];
  const float* b_qkv  = (const float*)d_in[3];
  const float* w_proj = (const float*)d_in[4];
  const float* b_proj = (const float*)d_in[5];
  const float* g1     = (const float*)d_in[6];
  const float* be1    = (const float*)d_in[7];
  const float* g2     = (const float*)d_in[8];
  const float* be2    = (const float*)d_in[9];
  const float* w_mlp1 = (const float*)d_in[10];
  const float* b_mlp1 = (const float*)d_in[11];
  const float* w_mlp2 = (const float*)d_in[12];
  const float* b_mlp2 = (const float*)d_in[13];

  char* ws = (char*)d_ws;
  ushort* WQKVT  = (ushort*)(ws + 0);
  ushort* WPROJT = (ushort*)(ws + 6291456);
  ushort* WMLP1T = (ushort*)(ws + 8388608);
  ushort* WMLP2T = (ushort*)(ws + 16777216);
  ushort* H      = (ushort*)(ws + 25165824);
  ushort* Qs     = (ushort*)(ws + 41943040);
  ushort* Ks     = (ushort*)(ws + 58720256);
  ushort* Vn     = (ushort*)(ws + 75497472);
  ushort* Vt     = (ushort*)(ws + 92274688);
  ushort* M1     = (ushort*)(ws + 41943040);
  float*  X1     = (float*)(ws + 109051904);

  // allow >64KB dynamic LDS (idempotent; host-side, capture-safe)
  hipFuncSetAttribute((const void*)gemm3_k<8, 0>, hipFuncAttributeMaxDynamicSharedMemorySize, 98304);
  hipFuncSetAttribute((const void*)gemm3_k<8, 2>, hipFuncAttributeMaxDynamicSharedMemorySize, 98304);
  hipFuncSetAttribute((const void*)gemm3_k<4, 1>, hipFuncAttributeMaxDynamicSharedMemorySize, 73728);

  castT_k<<<dim3(3072 / 32, 1024 / 32), 256, 0, stream>>>(w_qkv, WQKVT, 1024, 3072);
  castT_k<<<dim3(1024 / 32, 1024 / 32), 256, 0, stream>>>(w_proj, WPROJT, 1024, 1024);
  castT_k<<<dim3(4096 / 32, 1024 / 32), 256, 0, stream>>>(w_mlp1, WMLP1T, 1024, 4096);
  castT_k<<<dim3(1024 / 32, 4096 / 32), 256, 0, stream>>>(w_mlp2, WMLP2T, 4096, 1024);

  ln_k<<<8192, 256, 0, stream>>>(x, g1, be1, H);

  gemm3_k<8, 0><<<dim3(3072 / 256, 8192 / 256), 512, 98304, stream>>>(
      H, WQKVT, 8192, 3072, 1024, b_qkv, nullptr, nullptr, nullptr, Qs, Ks, Vn);

  vtrans_k<<<dim3(32, 64), 256, 0, stream>>>(Vn, Vt);

  attn_k<<<dim3(64, 32), 256, 0, stream>>>(Qs, Ks, Vt, H /* = O */);

  gemm3_k<4, 1><<<dim3(1024 / 256, 8192 / 128), 512, 73728, stream>>>(
      H, WPROJT, 8192, 1024, 1024, b_proj, x, X1, nullptr, nullptr, nullptr, nullptr);

  ln_k<<<8192, 256, 0, stream>>>(X1, g2, be2, H /* = H2 */);

  gemm3_k<8, 2><<<dim3(4096 / 256, 8192 / 256), 512, 98304, stream>>>(
      H, WMLP1T, 8192, 4096, 1024, b_mlp1, nullptr, nullptr, M1, nullptr, nullptr, nullptr);

  gemm3_k<4, 1><<<dim3(1024 / 256, 8192 / 128), 512, 73728, stream>>>(
      M1, WMLP2T, 8192, 1024, 4096, b_mlp2, X1, (float*)d_out, nullptr, nullptr, nullptr, nullptr);
}